// Round 1
// baseline (1432.892 us; speedup 1.0000x reference)
//
#include <hip/hip_runtime.h>

typedef __attribute__((ext_vector_type(8))) short frag_ab;   // 8 bf16 = 4 VGPRs
typedef __attribute__((ext_vector_type(4))) float frag_cd;   // 4 fp32 acc
typedef __attribute__((ext_vector_type(4))) short short4v;

__device__ __forceinline__ short f2bf(float f) {
  union { float f; unsigned u; } v; v.f = f;
  unsigned r = v.u + 0x7fffu + ((v.u >> 16) & 1u);   // RNE
  return (short)(r >> 16);
}

// ---------------------------------------------------------------------------
// proj: h = x @ pw + pb.  A=[128 rows][K=75 pad 96] bf16, B=[96][64] bf16.
// block 256 = 4 waves; wave w: rows w*32..w*32+31 (2 rowtiles of 16), 4 coltiles.
// ---------------------------------------------------------------------------
#define AS1 104   // LDS row stride (bf16) for K=96 tiles; 208B, 16B-aligned
__global__ __launch_bounds__(256) void proj_kernel(
    const float* __restrict__ x, const float* __restrict__ W,
    const float* __restrict__ bias, float* __restrict__ hout,
    short* __restrict__ hbf, int N)
{
  __shared__ __align__(16) short A[128 * AS1];
  __shared__ __align__(16) short Bt[64 * AS1];
  int t = threadIdx.x;
  int nb = blockIdx.x * 128;
  // stage A (x fp32 -> bf16, zero-pad k>=75 and rows>=N)
  for (int i = 0; i < 48; ++i) {                 // 128*96/256
    int q = i * 256 + t; int el = q / 96; int c = q - el * 96;
    int rg = nb + el;
    float v = (c < 75 && rg < N) ? x[rg * 75 + c] : 0.f;
    A[el * AS1 + c] = f2bf(v);
  }
  // stage Bt (transposed weights)
  for (int i = 0; i < 24; ++i) {                 // 96*64/256
    int q = i * 256 + t; int k = q >> 6; int n = q & 63;
    Bt[n * AS1 + k] = (k < 75) ? f2bf(W[k * 64 + n]) : (short)0;
  }
  __syncthreads();
  int wv = t >> 6, ln = t & 63;
  int lrow = ln & 15, lk = ln >> 4;
  frag_cd acc[2][4];
  for (int rt = 0; rt < 2; ++rt) for (int ct = 0; ct < 4; ++ct) {
    frag_cd z = {0.f, 0.f, 0.f, 0.f}; acc[rt][ct] = z;
  }
  for (int s = 0; s < 3; ++s) {
    frag_ab a0 = *(const frag_ab*)&A[(wv*32 + lrow) * AS1 + s*32 + lk*8];
    frag_ab a1 = *(const frag_ab*)&A[(wv*32 + 16 + lrow) * AS1 + s*32 + lk*8];
    for (int ct = 0; ct < 4; ++ct) {
      frag_ab b = *(const frag_ab*)&Bt[(ct*16 + lrow) * AS1 + s*32 + lk*8];
      acc[0][ct] = __builtin_amdgcn_mfma_f32_16x16x32_bf16(a0, b, acc[0][ct], 0, 0, 0);
      acc[1][ct] = __builtin_amdgcn_mfma_f32_16x16x32_bf16(a1, b, acc[1][ct], 0, 0, 0);
    }
  }
  float bv[4];
  for (int ct = 0; ct < 4; ++ct) bv[ct] = bias[ct*16 + lrow];
  for (int rt = 0; rt < 2; ++rt)
    for (int ct = 0; ct < 4; ++ct)
      for (int r = 0; r < 4; ++r) {
        int row = wv*32 + rt*16 + lk*4 + r;
        int rg = nb + row;
        if (rg < N) {
          float v = acc[rt][ct][r] + bv[ct];
          hout[rg * 64 + ct*16 + lrow] = v;
          hbf [rg * 64 + ct*16 + lrow] = f2bf(v);
        }
      }
}

// ---------------------------------------------------------------------------
// msg: for 128 edges/block: z=[h_bf16[src] | attr] (K=80 pad 96), m=leaky(z@W+b),
// atomicAdd into agg[dst]. Aggregation fused — m never hits HBM.
// ---------------------------------------------------------------------------
__global__ __launch_bounds__(256) void msg_kernel(
    const short* __restrict__ hbf, const float* __restrict__ attr,
    const int* __restrict__ src, const int* __restrict__ dst,
    const float* __restrict__ W, const float* __restrict__ bias,
    float* __restrict__ agg, int E)
{
  __shared__ __align__(16) short A[128 * AS1];
  __shared__ __align__(16) short Bt[64 * AS1];
  __shared__ int dstl[128];
  int t = threadIdx.x;
  int eb = blockIdx.x * 128;
  // stage Bt: W is [80][64] fp32
  for (int i = 0; i < 20; ++i) {                 // 80*64/256
    int q = i * 256 + t; int k = q >> 6; int n = q & 63;
    Bt[n * AS1 + k] = f2bf(W[q]);
  }
  for (int i = 0; i < 4; ++i) {                  // zero pad k=80..95
    int q = i * 256 + t; int k = 80 + (q >> 6); int n = q & 63;
    Bt[n * AS1 + k] = 0;
  }
  if (t < 128) dstl[t] = (eb + t < E) ? dst[eb + t] : 0;
  // stage A, h part: gather 16B chunks of h_bf16[src]
  for (int i = 0; i < 4; ++i) {                  // 128*8/256
    int q = i * 256 + t; int el = q >> 3; int c = q & 7;
    int e = eb + el;
    int s = (e < E) ? src[e] : 0;
    *(uint4*)&A[el * AS1 + c * 8] = *(const uint4*)&hbf[s * 64 + c * 8];
  }
  // stage A, attr part (fp32 -> bf16) + zero pad k=80..95
  for (int i = 0; i < 16; ++i) {                 // 128*32/256
    int q = i * 256 + t; int el = q >> 5; int c = q & 31;
    int e = eb + el;
    float v = (c < 16 && e < E) ? attr[e * 16 + c] : 0.f;
    A[el * AS1 + 64 + c] = f2bf(v);
  }
  __syncthreads();
  int wv = t >> 6, ln = t & 63;
  int lrow = ln & 15, lk = ln >> 4;
  frag_cd acc[2][4];
  for (int rt = 0; rt < 2; ++rt) for (int ct = 0; ct < 4; ++ct) {
    frag_cd z = {0.f, 0.f, 0.f, 0.f}; acc[rt][ct] = z;
  }
  for (int s = 0; s < 3; ++s) {
    frag_ab a0 = *(const frag_ab*)&A[(wv*32 + lrow) * AS1 + s*32 + lk*8];
    frag_ab a1 = *(const frag_ab*)&A[(wv*32 + 16 + lrow) * AS1 + s*32 + lk*8];
    for (int ct = 0; ct < 4; ++ct) {
      frag_ab b = *(const frag_ab*)&Bt[(ct*16 + lrow) * AS1 + s*32 + lk*8];
      acc[0][ct] = __builtin_amdgcn_mfma_f32_16x16x32_bf16(a0, b, acc[0][ct], 0, 0, 0);
      acc[1][ct] = __builtin_amdgcn_mfma_f32_16x16x32_bf16(a1, b, acc[1][ct], 0, 0, 0);
    }
  }
  float bv[4];
  for (int ct = 0; ct < 4; ++ct) bv[ct] = bias[ct*16 + lrow];
  for (int rt = 0; rt < 2; ++rt)
    for (int ct = 0; ct < 4; ++ct)
      for (int r = 0; r < 4; ++r) {
        int row = wv*32 + rt*16 + lk*4 + r;
        int e = eb + row;
        if (e < E) {
          float m = acc[rt][ct][r] + bv[ct];
          m = m > 0.f ? m : 0.1f * m;             // LeakyReLU(0.1)
          unsafeAtomicAdd(&agg[dstl[row] * 64 + ct*16 + lrow], m);
        }
      }
}

// ---------------------------------------------------------------------------
// update: h = [h_bf16 | agg] @ u1_w + b.  K=128 exact (4 ksteps). In-place on
// hout/hbf is safe: each block reads only its own 128 rows, staged before write.
// ---------------------------------------------------------------------------
#define AS2 136   // 272B row stride, 16B-aligned
__global__ __launch_bounds__(256) void upd_kernel(
    const short* __restrict__ hbf, const float* __restrict__ agg,
    const float* __restrict__ W, const float* __restrict__ bias,
    float* __restrict__ hout, short* __restrict__ hbfo, int N)
{
  __shared__ __align__(16) short A[128 * AS2];
  __shared__ __align__(16) short Bt[64 * AS2];
  int t = threadIdx.x;
  int nb = blockIdx.x * 128;
  // h half (already bf16, contiguous 16B copies)
  for (int i = 0; i < 4; ++i) {                  // 128*8/256
    int q = i * 256 + t; int el = q >> 3; int c = q & 7;
    int rg = nb + el;
    uint4 v = {0u, 0u, 0u, 0u};
    if (rg < N) v = *(const uint4*)&hbf[rg * 64 + c * 8];
    *(uint4*)&A[el * AS2 + c * 8] = v;
  }
  // agg half (fp32 -> bf16, float4 chunks)
  for (int i = 0; i < 8; ++i) {                  // 128*16/256
    int q = i * 256 + t; int el = q >> 4; int c = q & 15;
    int rg = nb + el;
    float4 v = make_float4(0.f, 0.f, 0.f, 0.f);
    if (rg < N) v = *(const float4*)&agg[rg * 64 + c * 4];
    short4v s4 = { f2bf(v.x), f2bf(v.y), f2bf(v.z), f2bf(v.w) };
    *(short4v*)&A[el * AS2 + 64 + c * 4] = s4;
  }
  // Bt: u1_w is [128][64] fp32
  for (int i = 0; i < 32; ++i) {                 // 128*64/256
    int q = i * 256 + t; int k = q >> 6; int n = q & 63;
    Bt[n * AS2 + k] = f2bf(W[q]);
  }
  __syncthreads();
  int wv = t >> 6, ln = t & 63;
  int lrow = ln & 15, lk = ln >> 4;
  frag_cd acc[2][4];
  for (int rt = 0; rt < 2; ++rt) for (int ct = 0; ct < 4; ++ct) {
    frag_cd z = {0.f, 0.f, 0.f, 0.f}; acc[rt][ct] = z;
  }
  for (int s = 0; s < 4; ++s) {
    frag_ab a0 = *(const frag_ab*)&A[(wv*32 + lrow) * AS2 + s*32 + lk*8];
    frag_ab a1 = *(const frag_ab*)&A[(wv*32 + 16 + lrow) * AS2 + s*32 + lk*8];
    for (int ct = 0; ct < 4; ++ct) {
      frag_ab b = *(const frag_ab*)&Bt[(ct*16 + lrow) * AS2 + s*32 + lk*8];
      acc[0][ct] = __builtin_amdgcn_mfma_f32_16x16x32_bf16(a0, b, acc[0][ct], 0, 0, 0);
      acc[1][ct] = __builtin_amdgcn_mfma_f32_16x16x32_bf16(a1, b, acc[1][ct], 0, 0, 0);
    }
  }
  float bv[4];
  for (int ct = 0; ct < 4; ++ct) bv[ct] = bias[ct*16 + lrow];
  for (int rt = 0; rt < 2; ++rt)
    for (int ct = 0; ct < 4; ++ct)
      for (int r = 0; r < 4; ++r) {
        int row = wv*32 + rt*16 + lk*4 + r;
        int rg = nb + row;
        if (rg < N) {
          float v = acc[rt][ct][r] + bv[ct];
          hout[rg * 64 + ct*16 + lrow] = v;
          hbfo[rg * 64 + ct*16 + lrow] = f2bf(v);
        }
      }
}

extern "C" void kernel_launch(void* const* d_in, const int* in_sizes, int n_in,
                              void* d_out, int out_size, void* d_ws, size_t ws_size,
                              hipStream_t stream) {
  const float* x    = (const float*)d_in[0];
  const int*   ei   = (const int*)d_in[1];
  const float* attr = (const float*)d_in[2];
  const float* pw   = (const float*)d_in[3];
  const float* pb   = (const float*)d_in[4];
  const float* u2w  = (const float*)d_in[5];
  const float* u2b  = (const float*)d_in[6];
  const float* u1w  = (const float*)d_in[7];
  const float* u1b  = (const float*)d_in[8];

  const int N = in_sizes[0] / 75;
  const int E = in_sizes[1] / 2;
  const int* src = ei;
  const int* dst = ei + E;

  float* hout = (float*)d_out;                       // fp32 h lives in d_out
  char*  ws   = (char*)d_ws;
  short* hbf  = (short*)ws;                          // N*64 bf16 = 12.8 MB
  float* agg  = (float*)(ws + (size_t)N * 64 * 2);   // N*64 fp32 = 25.6 MB

  const int NB = (N + 127) / 128;
  const int EB = (E + 127) / 128;

  proj_kernel<<<NB, 256, 0, stream>>>(x, pw, pb, hout, hbf, N);
  for (int l = 0; l < 3; ++l) {
    hipMemsetAsync(agg, 0, (size_t)N * 64 * 4, stream);
    msg_kernel<<<EB, 256, 0, stream>>>(hbf, attr, src, dst,
                                       u2w + l * 80 * 64, u2b + l * 64, agg, E);
    upd_kernel<<<NB, 256, 0, stream>>>(hbf, agg,
                                       u1w + l * 128 * 64, u1b + l * 64,
                                       hout, hbf, N);
  }
}

// Round 2
// 1264.485 us; speedup vs baseline: 1.1332x; 1.1332x over previous
//
#include <hip/hip_runtime.h>

typedef __attribute__((ext_vector_type(8))) short frag_ab;   // 8 bf16 = 4 VGPRs
typedef __attribute__((ext_vector_type(4))) float frag_cd;   // 4 fp32 acc
typedef __attribute__((ext_vector_type(4))) short short4v;

__device__ __forceinline__ short f2bf(float f) {
  union { float f; unsigned u; } v; v.f = f;
  unsigned r = v.u + 0x7fffu + ((v.u >> 16) & 1u);   // RNE
  return (short)(r >> 16);
}

// ---------------------------------------------------------------------------
// proj: h = x @ pw + pb.  A=[128 rows][K=75 pad 96] bf16, B=[96][64] bf16.
// ---------------------------------------------------------------------------
#define AS1 104   // LDS row stride (bf16) for K=96 tiles; 208B, 16B-aligned
__global__ __launch_bounds__(256) void proj_kernel(
    const float* __restrict__ x, const float* __restrict__ W,
    const float* __restrict__ bias, float* __restrict__ hout,
    short* __restrict__ hbf, int N)
{
  __shared__ __align__(16) short A[128 * AS1];
  __shared__ __align__(16) short Bt[64 * AS1];
  int t = threadIdx.x;
  int nb = blockIdx.x * 128;
  for (int i = 0; i < 48; ++i) {                 // 128*96/256
    int q = i * 256 + t; int el = q / 96; int c = q - el * 96;
    int rg = nb + el;
    float v = (c < 75 && rg < N) ? x[rg * 75 + c] : 0.f;
    A[el * AS1 + c] = f2bf(v);
  }
  for (int i = 0; i < 24; ++i) {                 // 96*64/256
    int q = i * 256 + t; int k = q >> 6; int n = q & 63;
    Bt[n * AS1 + k] = (k < 75) ? f2bf(W[k * 64 + n]) : (short)0;
  }
  __syncthreads();
  int wv = t >> 6, ln = t & 63;
  int lrow = ln & 15, lk = ln >> 4;
  frag_cd acc[2][4];
  for (int rt = 0; rt < 2; ++rt) for (int ct = 0; ct < 4; ++ct) {
    frag_cd z = {0.f, 0.f, 0.f, 0.f}; acc[rt][ct] = z;
  }
  for (int s = 0; s < 3; ++s) {
    frag_ab a0 = *(const frag_ab*)&A[(wv*32 + lrow) * AS1 + s*32 + lk*8];
    frag_ab a1 = *(const frag_ab*)&A[(wv*32 + 16 + lrow) * AS1 + s*32 + lk*8];
    for (int ct = 0; ct < 4; ++ct) {
      frag_ab b = *(const frag_ab*)&Bt[(ct*16 + lrow) * AS1 + s*32 + lk*8];
      acc[0][ct] = __builtin_amdgcn_mfma_f32_16x16x32_bf16(a0, b, acc[0][ct], 0, 0, 0);
      acc[1][ct] = __builtin_amdgcn_mfma_f32_16x16x32_bf16(a1, b, acc[1][ct], 0, 0, 0);
    }
  }
  float bv[4];
  for (int ct = 0; ct < 4; ++ct) bv[ct] = bias[ct*16 + lrow];
  for (int rt = 0; rt < 2; ++rt)
    for (int ct = 0; ct < 4; ++ct)
      for (int r = 0; r < 4; ++r) {
        int row = wv*32 + rt*16 + lk*4 + r;
        int rg = nb + row;
        if (rg < N) {
          float v = acc[rt][ct][r] + bv[ct];
          hout[rg * 64 + ct*16 + lrow] = v;
          hbf [rg * 64 + ct*16 + lrow] = f2bf(v);
        }
      }
}

// ---------------------------------------------------------------------------
// Counting sort of edges by dst: hist -> exclusive scan -> scatter perm.
// ---------------------------------------------------------------------------
__global__ __launch_bounds__(256) void hist_kernel(
    const int* __restrict__ dst, int* __restrict__ counts, int E)
{
  int i = blockIdx.x * 256 + threadIdx.x;
  if (i < E) atomicAdd(&counts[dst[i]], 1);
}

#define SCAN_TILE 2048
__global__ __launch_bounds__(256) void scan_k1(
    const int* __restrict__ counts, int* __restrict__ offsets,
    int* __restrict__ bsum, int n)
{
  __shared__ int ts[256];
  int t = threadIdx.x;
  int base = blockIdx.x * SCAN_TILE + t * 8;
  int v[8]; int s = 0;
  for (int j = 0; j < 8; ++j) { v[j] = (base + j < n) ? counts[base + j] : 0; s += v[j]; }
  ts[t] = s; __syncthreads();
  for (int off = 1; off < 256; off <<= 1) {
    int x = (t >= off) ? ts[t - off] : 0;
    __syncthreads();
    ts[t] += x;
    __syncthreads();
  }
  if (t == 255) bsum[blockIdx.x] = ts[255];
  int run = (t > 0) ? ts[t - 1] : 0;
  for (int j = 0; j < 8; ++j) { if (base + j < n) offsets[base + j] = run; run += v[j]; }
}

__global__ void scan_k2(int* bsum, int nb) {
  if (threadIdx.x == 0 && blockIdx.x == 0) {
    int run = 0;
    for (int b = 0; b < nb; ++b) { int x = bsum[b]; bsum[b] = run; run += x; }
  }
}

__global__ __launch_bounds__(256) void scan_k3(
    int* __restrict__ offsets, const int* __restrict__ bsum, int n)
{
  int add = bsum[blockIdx.x];
  int base = blockIdx.x * SCAN_TILE + threadIdx.x;
  for (int j = 0; j < 8; ++j) { int i = base + j * 256; if (i < n) offsets[i] += add; }
}

__global__ __launch_bounds__(256) void scatter_kernel(
    const int* __restrict__ src, const int* __restrict__ dst,
    int* __restrict__ offsets, int2* __restrict__ meta2,
    int* __restrict__ dsts, int E)
{
  int e = blockIdx.x * 256 + threadIdx.x;
  if (e < E) {
    int d = dst[e];
    int p = atomicAdd(&offsets[d], 1);
    meta2[p] = make_int2(src[e], e);
    dsts[p] = d;
  }
}

// ---------------------------------------------------------------------------
// msg v2: edges pre-sorted by dst. Per 128-edge block:
//   z = [h_bf16[src] | attr]  (K=80 pad 96),  m = leaky(z@W+b)  via MFMA,
//   m -> LDS M[128][66], then per-wave segmented reduction over sorted dst:
//   interior runs = complete global segment -> plain store; boundary -> atomic.
// LDS M aliases A/Bt (dead after K-loop). Total LDS 40448 B -> 4 blocks/CU.
// ---------------------------------------------------------------------------
#define MS 66
__global__ __launch_bounds__(256) void msg_kernel(
    const short* __restrict__ hbf, const float* __restrict__ attr,
    const int2* __restrict__ meta2, const int* __restrict__ dsts,
    const float* __restrict__ W, const float* __restrict__ bias,
    float* __restrict__ agg, int E)
{
  __shared__ __align__(16) char u[128 * AS1 * 2 + 64 * AS1 * 2];  // 39936 B
  __shared__ int dstl[128];
  short* A  = (short*)u;
  short* Bt = (short*)(u + 128 * AS1 * 2);
  float* M  = (float*)u;

  int t = threadIdx.x;
  int eb = blockIdx.x * 128;
  // stage Bt: W is [80][64] fp32 -> transposed bf16, pad K to 96
  for (int i = 0; i < 20; ++i) {                 // 80*64/256
    int q = i * 256 + t; int k = q >> 6; int n = q & 63;
    Bt[n * AS1 + k] = f2bf(W[q]);
  }
  for (int i = 0; i < 4; ++i) {                  // zero pad k=80..95
    int q = i * 256 + t; int k = 80 + (q >> 6); int n = q & 63;
    Bt[n * AS1 + k] = 0;
  }
  if (t < 128) dstl[t] = (eb + t < E) ? dsts[eb + t] : -1;
  // stage A, h part: gather 16B chunks of h_bf16[srcs[p]]
  for (int i = 0; i < 4; ++i) {                  // 128*8/256
    int q = i * 256 + t; int el = q >> 3; int c = q & 7;
    int p = eb + el;
    int s = 0;
    if (p < E) s = meta2[p].x;
    *(uint4*)&A[el * AS1 + c * 8] = *(const uint4*)&hbf[(size_t)s * 64 + c * 8];
  }
  // stage A, attr part via original edge id (random 64B gather) + zero pad
  for (int i = 0; i < 16; ++i) {                 // 128*32/256
    int q = i * 256 + t; int el = q >> 5; int c = q & 31;
    int p = eb + el;
    float v = 0.f;
    if (c < 16 && p < E) { int e2 = meta2[p].y; v = attr[(size_t)e2 * 16 + c]; }
    A[el * AS1 + 64 + c] = f2bf(v);
  }
  __syncthreads();

  int wv = t >> 6, ln = t & 63;
  int lrow = ln & 15, lk = ln >> 4;
  frag_cd acc[2][4];
  for (int rt = 0; rt < 2; ++rt) for (int ct = 0; ct < 4; ++ct) {
    frag_cd z = {0.f, 0.f, 0.f, 0.f}; acc[rt][ct] = z;
  }
  for (int s = 0; s < 3; ++s) {
    frag_ab a0 = *(const frag_ab*)&A[(wv*32 + lrow) * AS1 + s*32 + lk*8];
    frag_ab a1 = *(const frag_ab*)&A[(wv*32 + 16 + lrow) * AS1 + s*32 + lk*8];
    for (int ct = 0; ct < 4; ++ct) {
      frag_ab b = *(const frag_ab*)&Bt[(ct*16 + lrow) * AS1 + s*32 + lk*8];
      acc[0][ct] = __builtin_amdgcn_mfma_f32_16x16x32_bf16(a0, b, acc[0][ct], 0, 0, 0);
      acc[1][ct] = __builtin_amdgcn_mfma_f32_16x16x32_bf16(a1, b, acc[1][ct], 0, 0, 0);
    }
  }
  float bv[4];
  for (int ct = 0; ct < 4; ++ct) bv[ct] = bias[ct*16 + lrow];

  __syncthreads();   // A/Bt dead; M aliases them
  // write messages (bias + LeakyReLU applied) into M[row][col], stride 66
  for (int rt = 0; rt < 2; ++rt)
    for (int ct = 0; ct < 4; ++ct)
      for (int r = 0; r < 4; ++r) {
        int row = wv*32 + rt*16 + lk*4 + r;
        float m = acc[rt][ct][r] + bv[ct];
        m = m > 0.f ? m : 0.1f * m;
        M[row * MS + ct*16 + lrow] = m;
      }
  __syncthreads();

  // per-wave segmented reduction: wave wv owns rows [wv*32, wv*32+32),
  // lane ln owns column ln. dstl is lane-invariant -> wave-uniform loop.
  {
    int c = ln;
    int lo = wv * 32, hi = lo + 32;
    int i = lo;
    while (i < hi) {
      int d = dstl[i];
      int start = i;
      float s = 0.f;
      while (i < hi && dstl[i] == d) { s += M[i * MS + c]; ++i; }
      if (d >= 0) {
        float* dest = &agg[(size_t)d * 64 + c];
        if (start > lo && i < hi) *dest = s;      // complete segment: sole writer
        else unsafeAtomicAdd(dest, s);            // may continue in another chunk
      }
    }
  }
}

// ---------------------------------------------------------------------------
// update: h = [h_bf16 | agg] @ u1_w + b.  K=128 exact (4 ksteps).
// ---------------------------------------------------------------------------
#define AS2 136   // 272B row stride, 16B-aligned
__global__ __launch_bounds__(256) void upd_kernel(
    const short* __restrict__ hbf, const float* __restrict__ agg,
    const float* __restrict__ W, const float* __restrict__ bias,
    float* __restrict__ hout, short* __restrict__ hbfo, int N)
{
  __shared__ __align__(16) short A[128 * AS2];
  __shared__ __align__(16) short Bt[64 * AS2];
  int t = threadIdx.x;
  int nb = blockIdx.x * 128;
  for (int i = 0; i < 4; ++i) {                  // 128*8/256: h half (bf16 copy)
    int q = i * 256 + t; int el = q >> 3; int c = q & 7;
    int rg = nb + el;
    uint4 v = {0u, 0u, 0u, 0u};
    if (rg < N) v = *(const uint4*)&hbf[rg * 64 + c * 8];
    *(uint4*)&A[el * AS2 + c * 8] = v;
  }
  for (int i = 0; i < 8; ++i) {                  // 128*16/256: agg half fp32->bf16
    int q = i * 256 + t; int el = q >> 4; int c = q & 15;
    int rg = nb + el;
    float4 v = make_float4(0.f, 0.f, 0.f, 0.f);
    if (rg < N) v = *(const float4*)&agg[rg * 64 + c * 4];
    short4v s4 = { f2bf(v.x), f2bf(v.y), f2bf(v.z), f2bf(v.w) };
    *(short4v*)&A[el * AS2 + 64 + c * 4] = s4;
  }
  for (int i = 0; i < 32; ++i) {                 // 128*64/256: Bt
    int q = i * 256 + t; int k = q >> 6; int n = q & 63;
    Bt[n * AS2 + k] = f2bf(W[q]);
  }
  __syncthreads();
  int wv = t >> 6, ln = t & 63;
  int lrow = ln & 15, lk = ln >> 4;
  frag_cd acc[2][4];
  for (int rt = 0; rt < 2; ++rt) for (int ct = 0; ct < 4; ++ct) {
    frag_cd z = {0.f, 0.f, 0.f, 0.f}; acc[rt][ct] = z;
  }
  for (int s = 0; s < 4; ++s) {
    frag_ab a0 = *(const frag_ab*)&A[(wv*32 + lrow) * AS2 + s*32 + lk*8];
    frag_ab a1 = *(const frag_ab*)&A[(wv*32 + 16 + lrow) * AS2 + s*32 + lk*8];
    for (int ct = 0; ct < 4; ++ct) {
      frag_ab b = *(const frag_ab*)&Bt[(ct*16 + lrow) * AS2 + s*32 + lk*8];
      acc[0][ct] = __builtin_amdgcn_mfma_f32_16x16x32_bf16(a0, b, acc[0][ct], 0, 0, 0);
      acc[1][ct] = __builtin_amdgcn_mfma_f32_16x16x32_bf16(a1, b, acc[1][ct], 0, 0, 0);
    }
  }
  float bv[4];
  for (int ct = 0; ct < 4; ++ct) bv[ct] = bias[ct*16 + lrow];
  for (int rt = 0; rt < 2; ++rt)
    for (int ct = 0; ct < 4; ++ct)
      for (int r = 0; r < 4; ++r) {
        int row = wv*32 + rt*16 + lk*4 + r;
        int rg = nb + row;
        if (rg < N) {
          float v = acc[rt][ct][r] + bv[ct];
          hout[rg * 64 + ct*16 + lrow] = v;
          hbfo[rg * 64 + ct*16 + lrow] = f2bf(v);
        }
      }
}

extern "C" void kernel_launch(void* const* d_in, const int* in_sizes, int n_in,
                              void* d_out, int out_size, void* d_ws, size_t ws_size,
                              hipStream_t stream) {
  const float* x    = (const float*)d_in[0];
  const int*   ei   = (const int*)d_in[1];
  const float* attr = (const float*)d_in[2];
  const float* pw   = (const float*)d_in[3];
  const float* pb   = (const float*)d_in[4];
  const float* u2w  = (const float*)d_in[5];
  const float* u2b  = (const float*)d_in[6];
  const float* u1w  = (const float*)d_in[7];
  const float* u1b  = (const float*)d_in[8];

  const int N = in_sizes[0] / 75;
  const int E = in_sizes[1] / 2;
  const int* src = ei;
  const int* dst = ei + E;

  float* hout = (float*)d_out;                       // fp32 h lives in d_out
  char*  ws   = (char*)d_ws;
  size_t nh   = (size_t)N * 64;
  short* hbf  = (short*)ws;                          // nh*2 = 12.8 MB
  float* agg  = (float*)(ws + nh * 2);               // nh*4 = 25.6 MB
  int2*  meta2= (int2*)(ws + nh * 2 + nh * 4);       // E*8  = 12.8 MB
  int*   dsts = (int*)(ws + nh * 2 + nh * 4 + (size_t)E * 8); // E*4 = 6.4 MB
  // sort scratch overlays agg (dead until after scatter):
  int* counts  = (int*)agg;
  int* offsets = counts + N;
  int* bsum    = offsets + N;

  const int NB = (N + 127) / 128;
  const int EB = (E + 127) / 128;
  const int GE = (E + 255) / 256;
  const int NS = (N + SCAN_TILE - 1) / SCAN_TILE;

  proj_kernel<<<NB, 256, 0, stream>>>(x, pw, pb, hout, hbf, N);
  // counting sort by dst
  hipMemsetAsync(counts, 0, (size_t)N * 4, stream);
  hist_kernel<<<GE, 256, 0, stream>>>(dst, counts, E);
  scan_k1<<<NS, 256, 0, stream>>>(counts, offsets, bsum, N);
  scan_k2<<<1, 64, 0, stream>>>(bsum, NS);
  scan_k3<<<NS, 256, 0, stream>>>(offsets, bsum, N);
  scatter_kernel<<<GE, 256, 0, stream>>>(src, dst, offsets, meta2, dsts, E);

  for (int l = 0; l < 3; ++l) {
    hipMemsetAsync(agg, 0, nh * 4, stream);
    msg_kernel<<<EB, 256, 0, stream>>>(hbf, attr, meta2, dsts,
                                       u2w + l * 80 * 64, u2b + l * 64, agg, E);
    upd_kernel<<<NB, 256, 0, stream>>>(hbf, agg,
                                       u1w + l * 128 * 64, u1b + l * 64,
                                       hout, hbf, N);
  }
}

// Round 4
// 751.806 us; speedup vs baseline: 1.9059x; 1.6819x over previous
//
#include <hip/hip_runtime.h>

typedef __attribute__((ext_vector_type(8))) short frag_ab;   // 8 bf16 = 4 VGPRs
typedef __attribute__((ext_vector_type(4))) float frag_cd;   // 4 fp32 acc
typedef __attribute__((ext_vector_type(4))) short short4v;

__device__ __forceinline__ short f2bf(float f) {
  union { float f; unsigned u; } v; v.f = f;
  unsigned r = v.u + 0x7fffu + ((v.u >> 16) & 1u);   // RNE
  return (short)(r >> 16);
}

// ---------------------------------------------------------------------------
// wconv: convert fp32 weights [nmat][Keff][64] into MFMA B-fragment-ordered
// bf16: frag (s*4+ct), lane ln, element j = W[k=s*32+(ln>>4)*8+j][n=ct*16+(ln&15)]
// (zero-padded k >= Keff). Run ONCE; GEMMs then load B frags as single 16B
// global loads — no LDS staging for B.
// ---------------------------------------------------------------------------
__global__ void wconv(const float* __restrict__ W, short* __restrict__ out,
                      int Keff, int S, int nmat)
{
  int tid = blockIdx.x * 256 + threadIdx.x;
  int per = S * 4 * 64;
  if (tid >= nmat * per) return;
  int m = tid / per, r = tid % per;
  int s = r / 256, ct = (r >> 6) & 3, ln = r & 63;
  const float* Wm = W + (size_t)m * Keff * 64;
  __align__(16) short tmp[8];
  for (int j = 0; j < 8; ++j) {
    int k = s * 32 + (ln >> 4) * 8 + j;
    int n = ct * 16 + (ln & 15);
    tmp[j] = (k < Keff) ? f2bf(Wm[k * 64 + n]) : (short)0;
  }
  *(uint4*)&out[((size_t)m * per + (size_t)(s * 4 + ct) * 64 + ln) * 8] = *(uint4*)tmp;
}

// ---------------------------------------------------------------------------
// proj: hbf = bf16(x @ pw + pb).  A=[128][K=75 pad 96] bf16 in LDS; B frags
// from pre-converted wt (global, L2-resident).
// ---------------------------------------------------------------------------
#define AS1 104   // LDS row stride (bf16); 208 B = 13*16, 16B-aligned chunks
__global__ __launch_bounds__(256, 4) void proj_kernel(
    const float* __restrict__ x, const short* __restrict__ wt,
    const float* __restrict__ bias, short* __restrict__ hbf, int N)
{
  __shared__ __align__(16) short A[128 * AS1];
  int t = threadIdx.x;
  int nb = blockIdx.x * 128;
  int ln = t & 63;
  frag_ab bf[12];
  for (int s = 0; s < 3; ++s)
    for (int ct = 0; ct < 4; ++ct)
      bf[s * 4 + ct] = *(const frag_ab*)&wt[((size_t)(s * 4 + ct) * 64 + ln) * 8];
  for (int i = 0; i < 48; ++i) {                 // 128*96/256
    int q = i * 256 + t; int el = q / 96; int c = q - el * 96;
    int rg = nb + el;
    float v = (c < 75 && rg < N) ? x[rg * 75 + c] : 0.f;
    A[el * AS1 + c] = f2bf(v);
  }
  __syncthreads();
  int wv = t >> 6;
  int lrow = ln & 15, lk = ln >> 4;
  frag_cd acc[2][4];
  for (int rt = 0; rt < 2; ++rt) for (int ct = 0; ct < 4; ++ct) {
    frag_cd z = {0.f, 0.f, 0.f, 0.f}; acc[rt][ct] = z;
  }
  for (int s = 0; s < 3; ++s) {
    frag_ab a0 = *(const frag_ab*)&A[(wv*32 + lrow) * AS1 + s*32 + lk*8];
    frag_ab a1 = *(const frag_ab*)&A[(wv*32 + 16 + lrow) * AS1 + s*32 + lk*8];
    for (int ct = 0; ct < 4; ++ct) {
      acc[0][ct] = __builtin_amdgcn_mfma_f32_16x16x32_bf16(a0, bf[s*4+ct], acc[0][ct], 0, 0, 0);
      acc[1][ct] = __builtin_amdgcn_mfma_f32_16x16x32_bf16(a1, bf[s*4+ct], acc[1][ct], 0, 0, 0);
    }
  }
  float bv[4];
  for (int ct = 0; ct < 4; ++ct) bv[ct] = bias[ct*16 + lrow];
  for (int rt = 0; rt < 2; ++rt)
    for (int ct = 0; ct < 4; ++ct)
      for (int r = 0; r < 4; ++r) {
        int row = wv*32 + rt*16 + lk*4 + r;
        int rg = nb + row;
        if (rg < N) hbf[(size_t)rg * 64 + ct*16 + lrow] = f2bf(acc[rt][ct][r] + bv[ct]);
      }
}

// ---------------------------------------------------------------------------
// Counting sort of edges by dst + attr pre-permute (to bf16, sorted order).
// ---------------------------------------------------------------------------
__global__ __launch_bounds__(256) void hist_kernel(
    const int* __restrict__ dst, int* __restrict__ counts, int E)
{
  int i = blockIdx.x * 256 + threadIdx.x;
  if (i < E) atomicAdd(&counts[dst[i]], 1);
}

#define SCAN_TILE 2048
__global__ __launch_bounds__(256) void scan_k1(
    const int* __restrict__ counts, int* __restrict__ offsets,
    int* __restrict__ bsum, int n)
{
  __shared__ int ts[256];
  int t = threadIdx.x;
  int base = blockIdx.x * SCAN_TILE + t * 8;
  int v[8]; int s = 0;
  for (int j = 0; j < 8; ++j) { v[j] = (base + j < n) ? counts[base + j] : 0; s += v[j]; }
  ts[t] = s; __syncthreads();
  for (int off = 1; off < 256; off <<= 1) {
    int x = (t >= off) ? ts[t - off] : 0;
    __syncthreads();
    ts[t] += x;
    __syncthreads();
  }
  if (t == 255) bsum[blockIdx.x] = ts[255];
  int run = (t > 0) ? ts[t - 1] : 0;
  for (int j = 0; j < 8; ++j) { if (base + j < n) offsets[base + j] = run; run += v[j]; }
}

__global__ void scan_k2(int* bsum, int nb) {
  if (threadIdx.x == 0 && blockIdx.x == 0) {
    int run = 0;
    for (int b = 0; b < nb; ++b) { int x = bsum[b]; bsum[b] = run; run += x; }
  }
}

__global__ __launch_bounds__(256) void scan_k3(
    int* __restrict__ offsets, const int* __restrict__ bsum, int n)
{
  int add = bsum[blockIdx.x];
  int base = blockIdx.x * SCAN_TILE + threadIdx.x;
  for (int j = 0; j < 8; ++j) { int i = base + j * 256; if (i < n) offsets[i] += add; }
}

__global__ __launch_bounds__(256) void scatter_kernel(
    const int* __restrict__ src, const int* __restrict__ dst,
    const float* __restrict__ attr, int* __restrict__ offsets,
    int* __restrict__ srcs, int* __restrict__ dsts,
    short* __restrict__ attr_s, int E)
{
  int e = blockIdx.x * 256 + threadIdx.x;
  if (e < E) {
    int d = dst[e];
    int p = atomicAdd(&offsets[d], 1);
    srcs[p] = src[e];
    dsts[p] = d;
    __align__(16) short tmp[16];
    for (int c = 0; c < 16; ++c) tmp[c] = f2bf(attr[(size_t)e * 16 + c]);
    *(uint4*)&attr_s[(size_t)p * 16]     = *(uint4*)&tmp[0];
    *(uint4*)&attr_s[(size_t)p * 16 + 8] = *(uint4*)&tmp[8];
  }
}

// ---------------------------------------------------------------------------
// masks: per 32-row window of the sorted edge list, precompute
//   .x endmask      — bit i: row i is last of its dst-run within the window
//   .y completemask — bit i (at run end): run strictly interior to window →
//                     sole global writer → plain store instead of atomic.
// Layer-invariant; computed once.
// ---------------------------------------------------------------------------
__global__ __launch_bounds__(256) void masks_kernel(
    const int* __restrict__ dsts, uint2* __restrict__ masks, int E, int W)
{
  int w = blockIdx.x * 256 + threadIdx.x;
  if (w >= W) return;
  int base = w * 32;
  unsigned em = 0, cm = 0;
  int dprev = (base < E) ? dsts[base] : -1;
  int a = 0;
  for (int i = 1; i <= 32; ++i) {
    int d = (i < 32) ? ((base + i < E) ? dsts[base + i] : -1) : -2;
    if (d != dprev) {
      int end = i - 1;
      em |= 1u << end;
      if (a > 0 && end < 31) cm |= 1u << end;
      a = i; dprev = d;
    }
  }
  masks[w] = make_uint2(em, cm);
}

// ---------------------------------------------------------------------------
// msg: edges pre-sorted by dst. z=[hbf[src] | attr_s] (K=80 pad 96),
// m=leaky(z@W+b) via MFMA (B frags from global), m -> LDS M, then unrolled
// mask-driven segmented reduction. agg MUST be zeroed before launch (boundary
// runs accumulate via atomics).
// ---------------------------------------------------------------------------
#define MS 66
__global__ __launch_bounds__(256, 4) void msg_kernel(
    const short* __restrict__ hbf, const short* __restrict__ attr_s,
    const int* __restrict__ srcs, const int* __restrict__ dsts,
    const short* __restrict__ wt, const float* __restrict__ bias,
    const uint2* __restrict__ masks, float* __restrict__ agg, int E)
{
  __shared__ __align__(16) char u[128 * MS * 4];   // M(33792B) aliases A(26624B)
  __shared__ int dstl[128];
  short* A = (short*)u;
  float* M = (float*)u;

  int t = threadIdx.x;
  int eb = blockIdx.x * 128;
  int ln = t & 63;

  if (t < 128) dstl[t] = (eb + t < E) ? dsts[eb + t] : -1;

  frag_ab bf[12];
  for (int s = 0; s < 3; ++s)
    for (int ct = 0; ct < 4; ++ct)
      bf[s * 4 + ct] = *(const frag_ab*)&wt[((size_t)(s * 4 + ct) * 64 + ln) * 8];

  // h part: gather 16B chunks of hbf[srcs[p]]
  for (int i = 0; i < 4; ++i) {                  // 128*8/256
    int q = i * 256 + t; int el = q >> 3; int c = q & 7;
    int p = eb + el;
    int s = (p < E) ? srcs[p] : 0;
    *(uint4*)&A[el * AS1 + c * 8] = *(const uint4*)&hbf[(size_t)s * 64 + c * 8];
  }
  // attr part: coalesced bf16 stream, 1 chunk/thread; then zero pad k=80..95
  {
    int el = t >> 1, c = t & 1;
    int p = eb + el;
    uint4 v = {0u, 0u, 0u, 0u};
    if (p < E) v = *(const uint4*)&attr_s[(size_t)p * 16 + c * 8];
    *(uint4*)&A[el * AS1 + 64 + c * 8] = v;
    uint4 z = {0u, 0u, 0u, 0u};
    *(uint4*)&A[el * AS1 + 80 + c * 8] = z;
  }
  __syncthreads();

  int wv = t >> 6;
  int lrow = ln & 15, lk = ln >> 4;
  frag_cd acc[2][4];
  for (int rt = 0; rt < 2; ++rt) for (int ct = 0; ct < 4; ++ct) {
    frag_cd z = {0.f, 0.f, 0.f, 0.f}; acc[rt][ct] = z;
  }
  for (int s = 0; s < 3; ++s) {
    frag_ab a0 = *(const frag_ab*)&A[(wv*32 + lrow) * AS1 + s*32 + lk*8];
    frag_ab a1 = *(const frag_ab*)&A[(wv*32 + 16 + lrow) * AS1 + s*32 + lk*8];
    for (int ct = 0; ct < 4; ++ct) {
      acc[0][ct] = __builtin_amdgcn_mfma_f32_16x16x32_bf16(a0, bf[s*4+ct], acc[0][ct], 0, 0, 0);
      acc[1][ct] = __builtin_amdgcn_mfma_f32_16x16x32_bf16(a1, bf[s*4+ct], acc[1][ct], 0, 0, 0);
    }
  }
  float bv[4];
  for (int ct = 0; ct < 4; ++ct) bv[ct] = bias[ct*16 + lrow];

  __syncthreads();   // A dead; M aliases it
  for (int rt = 0; rt < 2; ++rt)
    for (int ct = 0; ct < 4; ++ct)
      for (int r = 0; r < 4; ++r) {
        int row = wv*32 + rt*16 + lk*4 + r;
        float m = acc[rt][ct][r] + bv[ct];
        m = m > 0.f ? m : 0.1f * m;              // LeakyReLU(0.1)
        M[row * MS + ct*16 + lrow] = m;
      }
  __syncthreads();

  // unrolled segmented reduction: wave wv owns rows [wv*32, wv*32+32),
  // lane ln owns column ln; masks are wave-uniform scalars.
  {
    uint2 mk = masks[blockIdx.x * 4 + wv];
    unsigned em = __builtin_amdgcn_readfirstlane(mk.x);
    unsigned cm = __builtin_amdgcn_readfirstlane(mk.y);
    float s = 0.f;
#pragma unroll
    for (int i = 0; i < 32; ++i) {
      s += M[(wv*32 + i) * MS + ln];
      if ((em >> i) & 1u) {
        int d = __builtin_amdgcn_readfirstlane(dstl[wv*32 + i]);
        if (d >= 0) {
          float* dest = &agg[(size_t)d * 64 + ln];
          if ((cm >> i) & 1u) *dest = s;
          else unsafeAtomicAdd(dest, s);
        }
        s = 0.f;
      }
    }
  }
}

// ---------------------------------------------------------------------------
// update: h = [hbf | agg] @ u1_w + b.  K=128 exact. B frags from global.
// fp32 output written only on last layer.
// ---------------------------------------------------------------------------
#define AS2 136   // 272 B row stride, 16B-aligned chunks
__global__ __launch_bounds__(256, 4) void upd_kernel(
    const short* __restrict__ hbf, const float* __restrict__ agg,
    const short* __restrict__ wt, const float* __restrict__ bias,
    float* __restrict__ hout, short* __restrict__ hbfo, int N, int last)
{
  __shared__ __align__(16) short A[128 * AS2];
  int t = threadIdx.x;
  int nb = blockIdx.x * 128;
  int ln = t & 63;
  for (int i = 0; i < 4; ++i) {                  // h half (bf16 copy)
    int q = i * 256 + t; int el = q >> 3; int c = q & 7;
    int rg = nb + el;
    uint4 v = {0u, 0u, 0u, 0u};
    if (rg < N) v = *(const uint4*)&hbf[(size_t)rg * 64 + c * 8];
    *(uint4*)&A[el * AS2 + c * 8] = v;
  }
  for (int i = 0; i < 8; ++i) {                  // agg half fp32->bf16
    int q = i * 256 + t; int el = q >> 4; int c = q & 15;
    int rg = nb + el;
    float4 v = make_float4(0.f, 0.f, 0.f, 0.f);
    if (rg < N) v = *(const float4*)&agg[(size_t)rg * 64 + c * 4];
    short4v s4 = { f2bf(v.x), f2bf(v.y), f2bf(v.z), f2bf(v.w) };
    *(short4v*)&A[el * AS2 + 64 + c * 4] = s4;
  }
  __syncthreads();
  int wv = t >> 6;
  int lrow = ln & 15, lk = ln >> 4;
  frag_cd acc[2][4];
  for (int rt = 0; rt < 2; ++rt) for (int ct = 0; ct < 4; ++ct) {
    frag_cd z = {0.f, 0.f, 0.f, 0.f}; acc[rt][ct] = z;
  }
  for (int s = 0; s < 4; ++s) {
    frag_ab a0 = *(const frag_ab*)&A[(wv*32 + lrow) * AS2 + s*32 + lk*8];
    frag_ab a1 = *(const frag_ab*)&A[(wv*32 + 16 + lrow) * AS2 + s*32 + lk*8];
    for (int ct = 0; ct < 4; ++ct) {
      frag_ab b = *(const frag_ab*)&wt[((size_t)(s * 4 + ct) * 64 + ln) * 8];
      acc[0][ct] = __builtin_amdgcn_mfma_f32_16x16x32_bf16(a0, b, acc[0][ct], 0, 0, 0);
      acc[1][ct] = __builtin_amdgcn_mfma_f32_16x16x32_bf16(a1, b, acc[1][ct], 0, 0, 0);
    }
  }
  float bv[4];
  for (int ct = 0; ct < 4; ++ct) bv[ct] = bias[ct*16 + lrow];
  for (int rt = 0; rt < 2; ++rt)
    for (int ct = 0; ct < 4; ++ct)
      for (int r = 0; r < 4; ++r) {
        int row = wv*32 + rt*16 + lk*4 + r;
        int rg = nb + row;
        if (rg < N) {
          float v = acc[rt][ct][r] + bv[ct];
          if (last) hout[(size_t)rg * 64 + ct*16 + lrow] = v;
          hbfo[(size_t)rg * 64 + ct*16 + lrow] = f2bf(v);
        }
      }
}

extern "C" void kernel_launch(void* const* d_in, const int* in_sizes, int n_in,
                              void* d_out, int out_size, void* d_ws, size_t ws_size,
                              hipStream_t stream) {
  const float* x    = (const float*)d_in[0];
  const int*   ei   = (const int*)d_in[1];
  const float* attr = (const float*)d_in[2];
  const float* pw   = (const float*)d_in[3];
  const float* pb   = (const float*)d_in[4];
  const float* u2w  = (const float*)d_in[5];
  const float* u2b  = (const float*)d_in[6];
  const float* u1w  = (const float*)d_in[7];
  const float* u1b  = (const float*)d_in[8];

  const int N = in_sizes[0] / 75;
  const int E = in_sizes[1] / 2;
  const int* src = ei;
  const int* dst = ei + E;

  float* hout = (float*)d_out;
  char*  ws   = (char*)d_ws;
  size_t nh   = (size_t)N * 64;
  size_t off  = 0;
  short* hbf   = (short*)(ws + off); off += nh * 2;              // 12.8 MB
  float* agg   = (float*)(ws + off); off += nh * 4;              // 25.6 MB
  int*   srcs  = (int*)  (ws + off); off += (size_t)E * 4;       //  6.4 MB
  int*   dsts  = (int*)  (ws + off); off += (size_t)E * 4;       //  6.4 MB
  short* attr_s= (short*)(ws + off); off += (size_t)E * 32;      // 51.2 MB
  const int EB = (E + 127) / 128;
  uint2* masks = (uint2*)(ws + off); off += (size_t)EB * 4 * 8;  //  0.4 MB
  short* projt = (short*)(ws + off); off += 3 * 4 * 64 * 8 * 2;
  short* u2t   = (short*)(ws + off); off += (size_t)3 * 3 * 4 * 64 * 8 * 2;
  short* u1t   = (short*)(ws + off); off += (size_t)3 * 4 * 4 * 64 * 8 * 2;
  // sort scratch overlays agg (dead until msg):
  int* counts  = (int*)agg;
  int* offsets = counts + N;
  int* bsum    = offsets + N;

  const int NB = (N + 127) / 128;
  const int GE = (E + 255) / 256;
  const int NS = (N + SCAN_TILE - 1) / SCAN_TILE;
  const int NW = EB * 4;

  // one-time preprocessing
  wconv<<<3, 256, 0, stream>>>(pw, projt, 75, 3, 1);
  wconv<<<9, 256, 0, stream>>>(u2w, u2t, 80, 3, 3);
  wconv<<<12, 256, 0, stream>>>(u1w, u1t, 128, 4, 3);
  proj_kernel<<<NB, 256, 0, stream>>>(x, projt, pb, hbf, N);
  hipMemsetAsync(counts, 0, (size_t)N * 4, stream);
  hist_kernel<<<GE, 256, 0, stream>>>(dst, counts, E);
  scan_k1<<<NS, 256, 0, stream>>>(counts, offsets, bsum, N);
  scan_k2<<<1, 64, 0, stream>>>(bsum, NS);
  scan_k3<<<NS, 256, 0, stream>>>(offsets, bsum, N);
  scatter_kernel<<<GE, 256, 0, stream>>>(src, dst, attr, offsets, srcs, dsts, attr_s, E);
  masks_kernel<<<(NW + 255) / 256, 256, 0, stream>>>(dsts, masks, E, NW);

  for (int l = 0; l < 3; ++l) {
    hipMemsetAsync(agg, 0, nh * 4, stream);     // boundary atomics need zeroed base
    msg_kernel<<<EB, 256, 0, stream>>>(hbf, attr_s, srcs, dsts,
                                       u2t + (size_t)l * 6144, u2b + l * 64,
                                       masks, agg, E);
    upd_kernel<<<NB, 256, 0, stream>>>(hbf, agg,
                                       u1t + (size_t)l * 8192, u1b + l * 64,
                                       hout, hbf, N, l == 2);
  }
}